// Round 3
// baseline (450.858 us; speedup 1.0000x reference)
//
#include <hip/hip_runtime.h>
#include <hip/hip_bf16.h>

// MLA absorbed causal attention, MI355X round 8 (3rd submit; infra failed 2x):
//  flash v6: v5 + (a) XOR-swizzle QK addresses decomposed into 2 hoisted
//  even/odd-lb base pointers (all ds_reads become base+imm, ~190 VALU/round
//  removed), (b) T13 defer-max rescale (skip O-rescale unless max grows by
//  >12 log2-units), (c) s_setprio(1) around both MFMA clusters.
// fp32 I/O. d_out = [ y (2*2048*1024) | c_kv (2*2048*512) ] fp32.

using bf16 = __hip_bfloat16;
using u32  = unsigned int;
using short8 = __attribute__((ext_vector_type(8))) short;   // 8 bf16 (4 VGPRs)
using f4     = __attribute__((ext_vector_type(4))) float;   // MFMA accumulator

static constexpr int kB  = 2;
static constexpr int kT  = 2048;
static constexpr int kC  = 1024;
static constexpr int kNH = 16;
static constexpr int kL  = 512;

__device__ inline u32 f2bf2(float a, float b) {
  bf16 ha = __float2bfloat16(a), hb = __float2bfloat16(b);
  unsigned short ua, ub;
  __builtin_memcpy(&ua, &ha, 2);
  __builtin_memcpy(&ub, &hb, 2);
  return (u32)ua | ((u32)ub << 16);
}
__device__ inline unsigned short f2bf(float x) {
  bf16 h = __float2bfloat16(x);
  unsigned short u; __builtin_memcpy(&u, &h, 2);
  return u;
}
__device__ inline short8 frag_ld(const void* p) {   // 16B aligned -> ds/global b128
  short8 r; __builtin_memcpy(&r, p, 16); return r;
}
// async global->LDS DMA, 16 B/lane. dest = wave-uniform base + lane*16.
__device__ inline void g2lds16(const bf16* g, bf16* l) {
  __builtin_amdgcn_global_load_lds(
      (const __attribute__((address_space(1))) u32*)g,
      (__attribute__((address_space(3))) u32*)l, 16, 0, 0);
}

// ---- fused flat casts: x, W_dq, W_uq, W_dkv, W_o -> bf16 ----
__global__ __launch_bounds__(256)
void casts_all(const float* __restrict__ x,   const float* __restrict__ wdq,
               const float* __restrict__ wuq, const float* __restrict__ wdkv,
               const float* __restrict__ wo,
               bf16* __restrict__ xb,   bf16* __restrict__ wdqb,
               bf16* __restrict__ wuqb, bf16* __restrict__ wdkvb,
               bf16* __restrict__ wob)
{
  long i = (long)(blockIdx.x * 256 + threadIdx.x) * 4;
  const float* s; bf16* d; long off;
  if      (i < 4194304) { s = x;    d = xb;    off = i; }
  else if (i < 4718592) { s = wdq;  d = wdqb;  off = i - 4194304; }
  else if (i < 5242880) { s = wuq;  d = wuqb;  off = i - 4718592; }
  else if (i < 5767168) { s = wdkv; d = wdkvb; off = i - 5242880; }
  else                  { s = wo;   d = wob;   off = i - 5767168; }
  float4 v = *(const float4*)(s + off);
  *(uint2*)((u32*)d + off / 2) = make_uint2(f2bf2(v.x, v.y), f2bf2(v.z, v.w));
}

// bf16 -> fp32 upcast (final c_kv output write). n multiple of 1024.
__global__ __launch_bounds__(256)
void upcast_kernel(const bf16* __restrict__ src, float* __restrict__ dst, int n)
{
  int i = (blockIdx.x * 256 + threadIdx.x) * 4;
  if (i < n) {
    uint2 v = *(const uint2*)((const u32*)src + i / 2);
    float4 o;
    o.x = __uint_as_float(v.x << 16);
    o.y = __uint_as_float(v.x & 0xffff0000u);
    o.z = __uint_as_float(v.y << 16);
    o.w = __uint_as_float(v.y & 0xffff0000u);
    *(float4*)(dst + i) = o;
  }
}

// ---- fused transpose-casts: z selects (src,dst,R,C); guards for shape ----
__global__ __launch_bounds__(256)
void tcasts_all(const float* __restrict__ wuq, const float* __restrict__ wuk,
                const float* __restrict__ wuv, const float* __restrict__ wdq,
                bf16* __restrict__ uqT, bf16* __restrict__ ukT,
                bf16* __restrict__ uvT, bf16* __restrict__ dqT)
{
  const int z = blockIdx.z;
  const float* src = z == 0 ? wuq : z == 1 ? wuk : z == 2 ? wuv : wdq;
  bf16* dst        = z == 0 ? uqT : z == 1 ? ukT : z == 2 ? uvT : dqT;
  const int R = (z == 3) ? 512 : 1024, C = (z == 3) ? 1024 : 512;
  const int r0 = blockIdx.x * 32, c0 = blockIdx.y * 32;
  if (r0 >= R || c0 >= C) return;
  __shared__ float s[32][33];
  const int x = threadIdx.x & 31, y = threadIdx.x >> 5;   // y: 0..7
#pragma unroll
  for (int i = 0; i < 4; ++i)
    s[y*4 + i][x] = src[(long)(r0 + y*4 + i) * C + c0 + x];
  __syncthreads();
  unsigned short* dp = (unsigned short*)dst;
#pragma unroll
  for (int i = 0; i < 4; ++i)
    dp[(long)(c0 + y*4 + i) * R + r0 + x] = f2bf(s[x][y*4 + i]);
}

// ckv [b][2048][512] -> ckvT [b][512][2048] (bf16).
__global__ __launch_bounds__(256)
void transpose_ckv(const bf16* __restrict__ src, bf16* __restrict__ dst)
{
  __shared__ unsigned short s[32][33];
  const int b = blockIdx.z, t0 = blockIdx.x * 32, l0 = blockIdx.y * 32;
  const int x = threadIdx.x & 31, y = threadIdx.x >> 5;
  const unsigned short* sp = (const unsigned short*)(src + (long)b * kT * kL);
  unsigned short* dp = (unsigned short*)(dst + (long)b * kL * kT);
#pragma unroll
  for (int i = 0; i < 4; ++i)
    s[y*4 + i][x] = sp[(long)(t0 + y*4 + i) * kL + l0 + x];
  __syncthreads();
#pragma unroll
  for (int i = 0; i < 4; ++i)
    dp[(long)(l0 + y*4 + i) * kT + t0 + x] = s[x][y*4 + i];
}

// ---------------------------------------------------------------------------
// NT MFMA GEMM (round-3 proven): C[m][n] = alpha * sum_k A[m][k] * B[n][k].
// ---------------------------------------------------------------------------
template<typename TCe>
__global__ __launch_bounds__(256)
void mm_nt(const bf16* __restrict__ A, int lda, long aHi, long aLo,
           const bf16* __restrict__ Bm, int ldb, long bHi, long bLo,
           TCe* __restrict__ Cm, int ldc, long cHi, long cLo,
           int K, float alpha)
{
  const int z = blockIdx.z;
  A  += (long)(z >> 4) * aHi + (long)(z & 15) * aLo;
  Bm += (long)(z >> 4) * bHi + (long)(z & 15) * bLo;
  Cm += (long)(z >> 4) * cHi + (long)(z & 15) * cLo;

  __shared__ __align__(16) bf16 As[64][72];
  __shared__ __align__(16) bf16 Bs[64][72];

  const int tid = threadIdx.x;
  const int w = tid >> 6, lane = tid & 63;
  const int quad = lane >> 4, lp = lane & 15;
  const int m0 = blockIdx.x * 64, n0 = blockIdx.y * 64;
  const int row = tid >> 2, cseg = (tid & 3) * 16;

  f4 acc[4];
#pragma unroll
  for (int i = 0; i < 4; ++i) acc[i] = f4{0.f, 0.f, 0.f, 0.f};

  for (int k0 = 0; k0 < K; k0 += 64) {
    const bf16* ag = A  + (long)(m0 + row) * lda + k0 + cseg;
    const bf16* bg = Bm + (long)(n0 + row) * ldb + k0 + cseg;
    uint4 a0 = *(const uint4*)ag, a1 = *(const uint4*)(ag + 8);
    uint4 b0 = *(const uint4*)bg, b1 = *(const uint4*)(bg + 8);
    __syncthreads();
    *(uint4*)&As[row][cseg] = a0; *(uint4*)&As[row][cseg + 8] = a1;
    *(uint4*)&Bs[row][cseg] = b0; *(uint4*)&Bs[row][cseg + 8] = b1;
    __syncthreads();

    short8 af0 = frag_ld(&As[w*16 + lp][quad * 8]);
    short8 af1 = frag_ld(&As[w*16 + lp][32 + quad * 8]);
#pragma unroll
    for (int nb = 0; nb < 4; ++nb) {
      short8 bf0 = frag_ld(&Bs[nb*16 + lp][quad * 8]);
      short8 bf1 = frag_ld(&Bs[nb*16 + lp][32 + quad * 8]);
      acc[nb] = __builtin_amdgcn_mfma_f32_16x16x32_bf16(af0, bf0, acc[nb], 0, 0, 0);
      acc[nb] = __builtin_amdgcn_mfma_f32_16x16x32_bf16(af1, bf1, acc[nb], 0, 0, 0);
    }
  }
#pragma unroll
  for (int nb = 0; nb < 4; ++nb)
#pragma unroll
    for (int r = 0; r < 4; ++r) {
      float v = alpha * acc[nb][r];
      long off = (long)(m0 + w*16 + quad*4 + r) * ldc + n0 + nb*16 + lp;
      if constexpr (__is_same(TCe, float)) Cm[off] = v;
      else ((unsigned short*)Cm)[off] = f2bf(v);
    }
}

// ---------------------------------------------------------------------------
// MFMA flash attention v6: 512-thread WG (8 waves), double-buffered DMA
// staging, one barrier per round (drain hidden behind compute).
// Wave w owns qb = 8*stripe + w (16 queries). Stripes pair j / 15-j: every
// WG does 68 rounds. Grid (8,16,2) = 256 WGs = 1/CU (LDS 138 KB).
// Ks[32][512]: phys 16B-block v of row r holds global block v ^ (r&7).
// KsT[512][32]: phys seg p of row rr holds global seg p ^ ((rr>>1)&3).
// v6: QK A-frag swizzle decomposed: (u^(lp&7))*8 = (lb>>1)*64
//     + ((lb&1)^(lp>>2&1))*32 + (quad^(lp&3))*8  -> 2 hoisted base ptrs,
//     all 32 QK ds_reads are base+imm. Defer-max rescale (THR=12 log2).
// ---------------------------------------------------------------------------
__global__ __launch_bounds__(512, 2)
void flash_mfma(bf16* __restrict__ qlat, const bf16* __restrict__ ckv,
                const bf16* __restrict__ ckvT)
{
  const int jj = blockIdx.x, h = blockIdx.y, b = blockIdx.z;
  const int tid = threadIdx.x;
  const int w = tid >> 6, lane = tid & 63;
  const int quad = lane >> 4, lp = lane & 15;

  __shared__ __align__(16) bf16 Ks[2][32 * 512];           // 64 KB
  __shared__ __align__(16) bf16 KsT[2][512 * 32];          // 64 KB
  __shared__ __align__(16) unsigned short Pbuf[8][16][40]; // 10 KB per-wave

  unsigned short (*Pw)[40] = Pbuf[w];
  u32* eb = (u32*)&Pbuf[w][0][0];                          // epilogue alias [16][20]

  const bf16* ckb = ckv  + (long)b * kT * kL;
  const bf16* ckt = ckvT + (long)b * kL * kT;

  // per-lane staging constants (element units)
  int ksOff[4], ktRow[4];
#pragma unroll
  for (int i = 0; i < 4; ++i) {
    int r = w * 4 + i;                              // Ks row 0..31
    ksOff[i] = r * 512 + ((lane & ~7) | ((lane ^ r) & 7)) * 8;
    ktRow[i] = (w * 4 + i) * 16 + (lane >> 2);      // KsT row 0..511
  }
  const int ktSeg = ((lane & 3) ^ ((lane >> 3) & 3)) * 8;   // (g*8)%4==0 -> lane-only

  // v6: hoisted QK A-frag swizzle decomposition (lane constants)
  const int cA    = lp & 7;                         // 3-bit row-xor constant
  const int laneA = lp * 512 + (quad ^ (cA & 3)) * 8;
  const int pOffE = (cA >> 2) * 32;                 // even-lb parity term
  const int pOffO = 32 - pOffE;                     // odd-lb parity term

  for (int half = 0; half < 2; ++half) {
    const int stripe = half ? (15 - jj) : jj;
    const int qb = 8 * stripe + w, q0 = qb * 16;
    bf16* qbase = qlat + (((long)(b * kNH + h)) * kT + q0) * kL;

    // persistent Q fragments (B-operand form): Q[q=lp][lb*32 + quad*8 + j]
    short8 qf[16];
#pragma unroll
    for (int lb = 0; lb < 16; ++lb)
      qf[lb] = frag_ld(qbase + (long)lp * kL + lb * 32 + quad * 8);

    f4 O[32];
#pragma unroll
    for (int ct = 0; ct < 32; ++ct) O[ct] = f4{0.f, 0.f, 0.f, 0.f};
    float m_r = -3e38f, l_r = 0.f;

    const int tmax = qb >> 1;
    const int nt = 4 * stripe + 4;

    // prologue: stage tile 0 into buffer 0
    {
      const bf16* kbase = ckb;                 // t = 0
      const bf16* tbase = ckt + ktSeg;
#pragma unroll
      for (int i = 0; i < 4; ++i) {
        g2lds16(kbase + ksOff[i], &Ks[0][(w * 4 + i) * 512]);
        g2lds16(tbase + (long)ktRow[i] * kT, &KsT[0][(w * 4 + i) * 512]);
      }
    }
    __syncthreads();

    for (int t = 0; t < nt; ++t) {
      const int bf = t & 1;
      if (t + 1 < nt) {                        // stage t+1 into other buffer
        const bf16* kbase = ckb + (long)(t + 1) * 32 * kL;
        const bf16* tbase = ckt + (long)(t + 1) * 32 + ktSeg;
#pragma unroll
        for (int i = 0; i < 4; ++i) {
          g2lds16(kbase + ksOff[i], &Ks[bf ^ 1][(w * 4 + i) * 512]);
          g2lds16(tbase + (long)ktRow[i] * kT, &KsT[bf ^ 1][(w * 4 + i) * 512]);
        }
      }

      if (t <= tmax) {
        // ---- S^T = K * Q^T : two 16-key m-tiles, hoisted base+imm reads ----
        const bf16* KsB = Ks[bf];
        const bf16* pe = KsB + laneA + pOffE;   // even lb
        const bf16* po = KsB + laneA + pOffO;   // odd lb
        f4 s0 = f4{0.f,0.f,0.f,0.f}, s1 = f4{0.f,0.f,0.f,0.f};
        __builtin_amdgcn_s_setprio(1);
#pragma unroll
        for (int lb2 = 0; lb2 < 8; ++lb2) {
          short8 a0 = frag_ld(pe + lb2 * 64);
          short8 a1 = frag_ld(pe + lb2 * 64 + 16 * 512);
          s0 = __builtin_amdgcn_mfma_f32_16x16x32_bf16(a0, qf[2*lb2], s0, 0, 0, 0);
          s1 = __builtin_amdgcn_mfma_f32_16x16x32_bf16(a1, qf[2*lb2], s1, 0, 0, 0);
          short8 a2 = frag_ld(po + lb2 * 64);
          short8 a3 = frag_ld(po + lb2 * 64 + 16 * 512);
          s0 = __builtin_amdgcn_mfma_f32_16x16x32_bf16(a2, qf[2*lb2+1], s0, 0, 0, 0);
          s1 = __builtin_amdgcn_mfma_f32_16x16x32_bf16(a3, qf[2*lb2+1], s1, 0, 0, 0);
        }
        __builtin_amdgcn_s_setprio(0);

        // ---- causal mask: key = t*32 + chain*16 + quad*4 + r, q = q0+lp ----
        if (t == tmax) {
          const int k0 = t * 32, q = q0 + lp;
#pragma unroll
          for (int r = 0; r < 4; ++r) {
            if (k0 + quad * 4 + r > q)      s0[r] = -3e38f;
            if (k0 + 16 + quad * 4 + r > q) s1[r] = -3e38f;
          }
        }

        // ---- online softmax, defer-max (T13): skip rescale unless the
        //      tile max exceeds the running max by >12 (log2 units; P<=2^12)
        float tm = fmaxf(fmaxf(fmaxf(s0[0], s0[1]), fmaxf(s0[2], s0[3])),
                         fmaxf(fmaxf(s1[0], s1[1]), fmaxf(s1[2], s1[3])));
        tm = fmaxf(tm, __shfl_xor(tm, 16, 64));
        tm = fmaxf(tm, __shfl_xor(tm, 32, 64));
        if (__ballot(tm > m_r + 12.0f)) {
          float mn = fmaxf(m_r, tm);
          float al = exp2f(m_r - mn);
#pragma unroll
          for (int ct = 0; ct < 32; ++ct) {
            O[ct][0] *= al; O[ct][1] *= al; O[ct][2] *= al; O[ct][3] *= al;
          }
          l_r *= al;
          m_r = mn;
        }
        float p0[4], p1[4], rs = 0.f;
#pragma unroll
        for (int r = 0; r < 4; ++r) {
          p0[r] = exp2f(s0[r] - m_r);
          p1[r] = exp2f(s1[r] - m_r);
          rs += p0[r] + p1[r];
        }
        rs += __shfl_xor(rs, 16, 64);
        rs += __shfl_xor(rs, 32, 64);
        l_r += rs;

        // ---- P^T -> per-wave LDS [q=lp][key], read back as B-frag ----
        *(uint2*)&Pw[lp][quad * 4] =
            make_uint2(f2bf2(p0[0], p0[1]), f2bf2(p0[2], p0[3]));
        *(uint2*)&Pw[lp][16 + quad * 4] =
            make_uint2(f2bf2(p1[0], p1[1]), f2bf2(p1[2], p1[3]));
        asm volatile("s_waitcnt lgkmcnt(0)" ::: "memory");
        short8 pb = frag_ld(&Pw[lp][quad * 8]);

        // ---- PV: O^T[lat][q] += V^T * P^T, A-frags from swizzled KsT ----
        const bf16* KtB = KsT[bf];
        const int pseg = (quad ^ ((lp >> 1) & 3)) * 8;
        __builtin_amdgcn_s_setprio(1);
#pragma unroll
        for (int ct = 0; ct < 32; ++ct) {
          short8 a = frag_ld(&KtB[(ct * 16 + lp) * 32 + pseg]);
          O[ct] = __builtin_amdgcn_mfma_f32_16x16x32_bf16(a, pb, O[ct], 0, 0, 0);
        }
        __builtin_amdgcn_s_setprio(0);
      }
      __syncthreads();   // closes round: buffers reusable; DMA t+1 drained here
    }

    // ---- epilogue: inv lane-local; transpose O^T via LDS slice; store ----
    {
      float inv = 1.0f / l_r;
      for (int cc = 0; cc < 16; ++cc) {
#pragma unroll
        for (int i = 0; i < 2; ++i) {
          int ct = cc * 2 + i;
          *(uint2*)&eb[lp * 20 + i * 8 + quad * 2] =
              make_uint2(f2bf2(O[ct][0] * inv, O[ct][1] * inv),
                         f2bf2(O[ct][2] * inv, O[ct][3] * inv));
        }
        asm volatile("s_waitcnt lgkmcnt(0)" ::: "memory");
        int qrow = lane >> 2, seg = lane & 3;
        uint4 v = *(const uint4*)&eb[qrow * 20 + seg * 4];
        *(uint4*)(qbase + (long)qrow * kL + cc * 32 + seg * 8) = v;
        asm volatile("s_waitcnt lgkmcnt(0)" ::: "memory");
      }
    }
    __syncthreads();     // half boundary: epilogue done before next prologue DMA
  }
}

// ---------------------------------------------------------------------------
extern "C" void kernel_launch(void* const* d_in, const int* in_sizes, int n_in,
                              void* d_out, int out_size, void* d_ws, size_t ws_size,
                              hipStream_t stream)
{
  const float* x     = (const float*)d_in[0];
  const float* W_dq  = (const float*)d_in[1];
  const float* W_uq  = (const float*)d_in[2];
  const float* W_dkv = (const float*)d_in[3];
  const float* W_uk  = (const float*)d_in[4];
  const float* W_uv  = (const float*)d_in[5];
  const float* W_o   = (const float*)d_in[6];

  float* y_out   = (float*)d_out;
  float* ckv_out = y_out + (long)kB * kT * kC;

  // workspace layout (max 101,711,872 B, proven bound)
  char* ws = (char*)d_ws;
  bf16* q_lat  = (bf16*)(ws + 0);            // 64 MB  (y_lat in place)
  bf16* ckv_b  = (bf16*)(ws + 67108864);     //  4 MB
  bf16* ckvT   = (bf16*)(ws + 71303168);     //  4 MB
  bf16* xb     = (bf16*)(ws + 75497472);     //  8 MB
  bf16* q_lowb = (bf16*)(ws + 83886080);     //  4 MB
  bf16* qfullb = (bf16*)(ws + 88080384);     //  8 MB (scratch overlap below)
  bf16* W_uqTb = (bf16*)(ws + 88080384);     //  1 MB  [dead before qfullb write]
  bf16* W_ukTb = (bf16*)(ws + 89128960);     //  1 MB
  bf16* W_uvTb = (bf16*)(ws + 90177536);     //  1 MB
  bf16* W_dqTb = (bf16*)(ws + 91226112);     //  1 MB
  bf16* W_ob   = (bf16*)(ws + 92274688);     //  2 MB
  bf16* tmpT   = (bf16*)(ws + 94371840);     // 0.5 MB
  bf16* k_effT = (bf16*)(ws + 96468992);     //  1 MB  [512 l][1024 c]
  bf16* v_effT = (bf16*)(ws + 97517568);     //  1 MB  [1024 j][512 l]
  bf16* W_dqb  = (bf16*)(ws + 98566144);     //  1 MB
  bf16* W_uqb  = (bf16*)(ws + 99614720);     //  1 MB
  bf16* W_dkvb = (bf16*)(ws + 100663296);    //  1 MB

  const dim3 blk(256);
  const long TC = (long)kT * kC, TL = (long)kT * kL;
  const float kScale = 0.125f * 1.44269504088896f;   // 1/sqrt(hs) * log2(e)

  casts_all<<<dim3(6656), blk, 0, stream>>>(
      x, W_dq, W_uq, W_dkv, W_o, xb, W_dqb, W_uqb, W_dkvb, W_ob);
  tcasts_all<<<dim3(32, 32, 4), blk, 0, stream>>>(
      W_uq, W_uk, W_uv, W_dq, W_uqTb, W_ukTb, W_uvTb, W_dqTb);

  mm_nt<bf16><<<dim3(8, 8, 1), blk, 0, stream>>>(
      W_ukTb, 1024, 0, 0, W_uqTb, 1024, 0, 0, tmpT, 512, 0, 0, 1024, 1.0f);
  mm_nt<bf16><<<dim3(8, 16, 1), blk, 0, stream>>>(
      tmpT, 512, 0, 0, W_dqTb, 512, 0, 0, k_effT, 1024, 0, 0, 512, kScale);
  mm_nt<bf16><<<dim3(16, 8, 1), blk, 0, stream>>>(
      W_ob, 1024, 0, 0, W_uvTb, 1024, 0, 0, v_effT, 512, 0, 0, 1024, 1.0f);
  mm_nt<bf16><<<dim3(64, 8, 1), blk, 0, stream>>>(
      xb, 1024, 0, 0, W_dqb, 1024, 0, 0, q_lowb, 512, 0, 0, 1024, 1.0f);
  mm_nt<bf16><<<dim3(64, 16, 1), blk, 0, stream>>>(
      q_lowb, 512, 0, 0, W_uqb, 512, 0, 0, qfullb, 1024, 0, 0, 512, 1.0f);
  // c_kv -> bf16 ckv_b directly (no early d_out write)
  mm_nt<bf16><<<dim3(64, 8, 1), blk, 0, stream>>>(
      xb, 1024, 0, 0, W_dkvb, 1024, 0, 0, ckv_b, 512, 0, 0, 1024, 1.0f);
  transpose_ckv<<<dim3(64, 16, 2), blk, 0, stream>>>(ckv_b, ckvT);
  mm_nt<bf16><<<dim3(32, 8, 32), blk, 0, stream>>>(
      qfullb, 1024, TC, 64,
      k_effT, 1024, 0, 64,
      q_lat, 512, (long)kNH * TL, TL,
      64, 1.0f);
  flash_mfma<<<dim3(8, 16, 2), dim3(512), 0, stream>>>(q_lat, ckv_b, ckvT);
  mm_nt<float><<<dim3(32, 1, 32), blk, 0, stream>>>(
      q_lat, 512, (long)kNH * TL, TL,
      v_effT, 512, 0, (long)64 * 512,
      y_out, 1024, TC, 64,
      512, 1.0f);
  // FINAL kernel: write the fp32 c_kv output tail last.
  upcast_kernel<<<dim3(2048), blk, 0, stream>>>(ckv_b, ckv_out, 2097152);

  (void)in_sizes; (void)n_in; (void)out_size; (void)ws_size;
}

// Round 4
// 434.975 us; speedup vs baseline: 1.0365x; 1.0365x over previous
//
#include <hip/hip_runtime.h>
#include <hip/hip_bf16.h>

// MLA absorbed causal attention, MI355X round 9:
//  flash v7: LDS-bandwidth attack. PV switched to mfma_f32_32x32x16_bf16
//  (32 FLOP per LDS byte vs 16): wave-pairs share a 32-query block; P/alpha/l
//  exchanged via pair-shared LDS (one extra barrier per round); each wave
//  computes PV for its 256-lat half -> PV A-frag reads halve (32->16 b128).
//  QK/softmax keep the proven 16x16 path with v6's hoisted swizzle pointers.
//  setprio REMOVED (lockstep waves: it delayed DMA issue, -7% measured).
// fp32 I/O. d_out = [ y (2*2048*1024) | c_kv (2*2048*512) ] fp32.

using bf16 = __hip_bfloat16;
using u32  = unsigned int;
using short8 = __attribute__((ext_vector_type(8))) short;   // 8 bf16 (4 VGPRs)
using f4     = __attribute__((ext_vector_type(4))) float;   // 16x16 accumulator
using f16v   = __attribute__((ext_vector_type(16))) float;  // 32x32 accumulator

static constexpr int kB  = 2;
static constexpr int kT  = 2048;
static constexpr int kC  = 1024;
static constexpr int kNH = 16;
static constexpr int kL  = 512;

__device__ inline u32 f2bf2(float a, float b) {
  bf16 ha = __float2bfloat16(a), hb = __float2bfloat16(b);
  unsigned short ua, ub;
  __builtin_memcpy(&ua, &ha, 2);
  __builtin_memcpy(&ub, &hb, 2);
  return (u32)ua | ((u32)ub << 16);
}
__device__ inline unsigned short f2bf(float x) {
  bf16 h = __float2bfloat16(x);
  unsigned short u; __builtin_memcpy(&u, &h, 2);
  return u;
}
__device__ inline short8 frag_ld(const void* p) {   // 16B aligned -> ds/global b128
  short8 r; __builtin_memcpy(&r, p, 16); return r;
}
// async global->LDS DMA, 16 B/lane. dest = wave-uniform base + lane*16.
__device__ inline void g2lds16(const bf16* g, bf16* l) {
  __builtin_amdgcn_global_load_lds(
      (const __attribute__((address_space(1))) u32*)g,
      (__attribute__((address_space(3))) u32*)l, 16, 0, 0);
}

// ---- fused flat casts: x, W_dq, W_uq, W_dkv, W_o -> bf16 ----
__global__ __launch_bounds__(256)
void casts_all(const float* __restrict__ x,   const float* __restrict__ wdq,
               const float* __restrict__ wuq, const float* __restrict__ wdkv,
               const float* __restrict__ wo,
               bf16* __restrict__ xb,   bf16* __restrict__ wdqb,
               bf16* __restrict__ wuqb, bf16* __restrict__ wdkvb,
               bf16* __restrict__ wob)
{
  long i = (long)(blockIdx.x * 256 + threadIdx.x) * 4;
  const float* s; bf16* d; long off;
  if      (i < 4194304) { s = x;    d = xb;    off = i; }
  else if (i < 4718592) { s = wdq;  d = wdqb;  off = i - 4194304; }
  else if (i < 5242880) { s = wuq;  d = wuqb;  off = i - 4718592; }
  else if (i < 5767168) { s = wdkv; d = wdkvb; off = i - 5242880; }
  else                  { s = wo;   d = wob;   off = i - 5767168; }
  float4 v = *(const float4*)(s + off);
  *(uint2*)((u32*)d + off / 2) = make_uint2(f2bf2(v.x, v.y), f2bf2(v.z, v.w));
}

// bf16 -> fp32 upcast (final c_kv output write). n multiple of 1024.
__global__ __launch_bounds__(256)
void upcast_kernel(const bf16* __restrict__ src, float* __restrict__ dst, int n)
{
  int i = (blockIdx.x * 256 + threadIdx.x) * 4;
  if (i < n) {
    uint2 v = *(const uint2*)((const u32*)src + i / 2);
    float4 o;
    o.x = __uint_as_float(v.x << 16);
    o.y = __uint_as_float(v.x & 0xffff0000u);
    o.z = __uint_as_float(v.y << 16);
    o.w = __uint_as_float(v.y & 0xffff0000u);
    *(float4*)(dst + i) = o;
  }
}

// ---- fused transpose-casts: z selects (src,dst,R,C); guards for shape ----
__global__ __launch_bounds__(256)
void tcasts_all(const float* __restrict__ wuq, const float* __restrict__ wuk,
                const float* __restrict__ wuv, const float* __restrict__ wdq,
                bf16* __restrict__ uqT, bf16* __restrict__ ukT,
                bf16* __restrict__ uvT, bf16* __restrict__ dqT)
{
  const int z = blockIdx.z;
  const float* src = z == 0 ? wuq : z == 1 ? wuk : z == 2 ? wuv : wdq;
  bf16* dst        = z == 0 ? uqT : z == 1 ? ukT : z == 2 ? uvT : dqT;
  const int R = (z == 3) ? 512 : 1024, C = (z == 3) ? 1024 : 512;
  const int r0 = blockIdx.x * 32, c0 = blockIdx.y * 32;
  if (r0 >= R || c0 >= C) return;
  __shared__ float s[32][33];
  const int x = threadIdx.x & 31, y = threadIdx.x >> 5;   // y: 0..7
#pragma unroll
  for (int i = 0; i < 4; ++i)
    s[y*4 + i][x] = src[(long)(r0 + y*4 + i) * C + c0 + x];
  __syncthreads();
  unsigned short* dp = (unsigned short*)dst;
#pragma unroll
  for (int i = 0; i < 4; ++i)
    dp[(long)(c0 + y*4 + i) * R + r0 + x] = f2bf(s[x][y*4 + i]);
}

// ckv [b][2048][512] -> ckvT [b][512][2048] (bf16).
__global__ __launch_bounds__(256)
void transpose_ckv(const bf16* __restrict__ src, bf16* __restrict__ dst)
{
  __shared__ unsigned short s[32][33];
  const int b = blockIdx.z, t0 = blockIdx.x * 32, l0 = blockIdx.y * 32;
  const int x = threadIdx.x & 31, y = threadIdx.x >> 5;
  const unsigned short* sp = (const unsigned short*)(src + (long)b * kT * kL);
  unsigned short* dp = (unsigned short*)(dst + (long)b * kL * kT);
#pragma unroll
  for (int i = 0; i < 4; ++i)
    s[y*4 + i][x] = sp[(long)(t0 + y*4 + i) * kL + l0 + x];
  __syncthreads();
#pragma unroll
  for (int i = 0; i < 4; ++i)
    dp[(long)(l0 + y*4 + i) * kT + t0 + x] = s[x][y*4 + i];
}

// ---------------------------------------------------------------------------
// NT MFMA GEMM (round-3 proven): C[m][n] = alpha * sum_k A[m][k] * B[n][k].
// ---------------------------------------------------------------------------
template<typename TCe>
__global__ __launch_bounds__(256)
void mm_nt(const bf16* __restrict__ A, int lda, long aHi, long aLo,
           const bf16* __restrict__ Bm, int ldb, long bHi, long bLo,
           TCe* __restrict__ Cm, int ldc, long cHi, long cLo,
           int K, float alpha)
{
  const int z = blockIdx.z;
  A  += (long)(z >> 4) * aHi + (long)(z & 15) * aLo;
  Bm += (long)(z >> 4) * bHi + (long)(z & 15) * bLo;
  Cm += (long)(z >> 4) * cHi + (long)(z & 15) * cLo;

  __shared__ __align__(16) bf16 As[64][72];
  __shared__ __align__(16) bf16 Bs[64][72];

  const int tid = threadIdx.x;
  const int w = tid >> 6, lane = tid & 63;
  const int quad = lane >> 4, lp = lane & 15;
  const int m0 = blockIdx.x * 64, n0 = blockIdx.y * 64;
  const int row = tid >> 2, cseg = (tid & 3) * 16;

  f4 acc[4];
#pragma unroll
  for (int i = 0; i < 4; ++i) acc[i] = f4{0.f, 0.f, 0.f, 0.f};

  for (int k0 = 0; k0 < K; k0 += 64) {
    const bf16* ag = A  + (long)(m0 + row) * lda + k0 + cseg;
    const bf16* bg = Bm + (long)(n0 + row) * ldb + k0 + cseg;
    uint4 a0 = *(const uint4*)ag, a1 = *(const uint4*)(ag + 8);
    uint4 b0 = *(const uint4*)bg, b1 = *(const uint4*)(bg + 8);
    __syncthreads();
    *(uint4*)&As[row][cseg] = a0; *(uint4*)&As[row][cseg + 8] = a1;
    *(uint4*)&Bs[row][cseg] = b0; *(uint4*)&Bs[row][cseg + 8] = b1;
    __syncthreads();

    short8 af0 = frag_ld(&As[w*16 + lp][quad * 8]);
    short8 af1 = frag_ld(&As[w*16 + lp][32 + quad * 8]);
#pragma unroll
    for (int nb = 0; nb < 4; ++nb) {
      short8 bf0 = frag_ld(&Bs[nb*16 + lp][quad * 8]);
      short8 bf1 = frag_ld(&Bs[nb*16 + lp][32 + quad * 8]);
      acc[nb] = __builtin_amdgcn_mfma_f32_16x16x32_bf16(af0, bf0, acc[nb], 0, 0, 0);
      acc[nb] = __builtin_amdgcn_mfma_f32_16x16x32_bf16(af1, bf1, acc[nb], 0, 0, 0);
    }
  }
#pragma unroll
  for (int nb = 0; nb < 4; ++nb)
#pragma unroll
    for (int r = 0; r < 4; ++r) {
      float v = alpha * acc[nb][r];
      long off = (long)(m0 + w*16 + quad*4 + r) * ldc + n0 + nb*16 + lp;
      if constexpr (__is_same(TCe, float)) Cm[off] = v;
      else ((unsigned short*)Cm)[off] = f2bf(v);
    }
}

// ---------------------------------------------------------------------------
// MFMA flash attention v7: 512-thread WG (8 waves = 4 pairs), double-buffered
// DMA staging. Pair p = waves {2p, 2p+1} owns 32 queries; wave half ph = w&1
// owns lat range [ph*256, ph*256+256) for PV.
// Round: stage t+1 -> QK(16x16, own 16q) + softmax + write P/alpha to pair
// LDS -> barrier A -> rescale O (pair alpha) + PV(32x32x16, half lat, 16
// A-frag reads) -> barrier B.
// Ks[32][512]: phys 16B-block v of row r holds global block v ^ (r&7).
// KsT[512][32]: phys seg s of row rr holds global seg s ^ ((rr>>1)&3).
// tmax = (8*stripe + w)>>1 is pair-uniform ((2p)>>1 == (2p+1)>>1).
// Epilogue: per-wave transpose slice aliased on Ks[1] (dead at epilogue).
// ---------------------------------------------------------------------------
__global__ __launch_bounds__(512, 2)
void flash_mfma(bf16* __restrict__ qlat, const bf16* __restrict__ ckv,
                const bf16* __restrict__ ckvT)
{
  const int jj = blockIdx.x, h = blockIdx.y, b = blockIdx.z;
  const int tid = threadIdx.x;
  const int w = tid >> 6, lane = tid & 63;
  const int quad = lane >> 4, lp = lane & 15;
  const int hi = lane >> 5, la = lane & 31;
  const int p = w >> 1, ph = w & 1;         // pair index, lat-half index
  const int L0 = ph * 256;                  // PV lat-half base

  __shared__ __align__(16) bf16 Ks[2][32 * 512];           // 64 KB
  __shared__ __align__(16) bf16 KsT[2][512 * 32];          // 64 KB
  __shared__ __align__(16) unsigned short Pp[4][32][40];   // 10 KB pair P
  __shared__ float Axf[4][32];                             // pair alpha / l

  const bf16* ckb = ckv  + (long)b * kT * kL;
  const bf16* ckt = ckvT + (long)b * kL * kT;

  // per-lane staging constants (element units)
  int ksOff[4], ktRow[4];
#pragma unroll
  for (int i = 0; i < 4; ++i) {
    int r = w * 4 + i;                              // Ks row 0..31
    ksOff[i] = r * 512 + ((lane & ~7) | ((lane ^ r) & 7)) * 8;
    ktRow[i] = (w * 4 + i) * 16 + (lane >> 2);      // KsT row 0..511
  }
  const int ktSeg = ((lane & 3) ^ ((lane >> 3) & 3)) * 8;   // lane-only

  // QK A-frag swizzle decomposition (v6, proven neutral-positive)
  const int cA    = lp & 7;
  const int laneA = lp * 512 + (quad ^ (cA & 3)) * 8;
  const int pOffE = (cA >> 2) * 32;
  const int pOffO = 32 - pOffE;

  // PV A-frag lane constants: read KsT[L0 + lb*32 + la][seg], seg swizzled
  const int cs = (la >> 1) & 3;
  const int pvBase = (L0 + la) * 32;                // + lb*1024 + offk
  const int offk0 = ((0 + hi) ^ cs) * 8;            // kstep 0 (keys 0-15)
  const int offk1 = ((2 + hi) ^ cs) * 8;            // kstep 1 (keys 16-31)

  for (int half = 0; half < 2; ++half) {
    const int stripe = half ? (15 - jj) : jj;
    const int qb = 8 * stripe + w, q0 = qb * 16;           // wave's 16 queries
    const int q0p = stripe * 128 + p * 32;                 // pair's 32 queries
    bf16* qbase  = qlat + (((long)(b * kNH + h)) * kT + q0) * kL;
    bf16* qbaseP = qlat + (((long)(b * kNH + h)) * kT + q0p) * kL;

    // persistent Q fragments (B-operand form): Q[q=lp][lb*32 + quad*8 + j]
    short8 qf[16];
#pragma unroll
    for (int lb = 0; lb < 16; ++lb)
      qf[lb] = frag_ld(qbase + (long)lp * kL + lb * 32 + quad * 8);

    f16v O32[8];
#pragma unroll
    for (int ct = 0; ct < 8; ++ct)
#pragma unroll
      for (int j = 0; j < 16; ++j) O32[ct][j] = 0.f;
    float m_r = -3e38f, l_r = 0.f;

    const int tmax = qb >> 1;                // pair-uniform
    const int nt = 4 * stripe + 4;

    // prologue: stage tile 0 into buffer 0
    {
      const bf16* kbase = ckb;                 // t = 0
      const bf16* tbase = ckt + ktSeg;
#pragma unroll
      for (int i = 0; i < 4; ++i) {
        g2lds16(kbase + ksOff[i], &Ks[0][(w * 4 + i) * 512]);
        g2lds16(tbase + (long)ktRow[i] * kT, &KsT[0][(w * 4 + i) * 512]);
      }
    }
    __syncthreads();

    for (int t = 0; t < nt; ++t) {
      const int bf = t & 1;
      if (t + 1 < nt) {                        // stage t+1 into other buffer
        const bf16* kbase = ckb + (long)(t + 1) * 32 * kL;
        const bf16* tbase = ckt + (long)(t + 1) * 32 + ktSeg;
#pragma unroll
        for (int i = 0; i < 4; ++i) {
          g2lds16(kbase + ksOff[i], &Ks[bf ^ 1][(w * 4 + i) * 512]);
          g2lds16(tbase + (long)ktRow[i] * kT, &KsT[bf ^ 1][(w * 4 + i) * 512]);
        }
      }

      if (t <= tmax) {
        // ---- S^T = K * Q^T : two 16-key m-tiles, hoisted base+imm reads ----
        const bf16* KsB = Ks[bf];
        const bf16* pe = KsB + laneA + pOffE;   // even lb
        const bf16* po = KsB + laneA + pOffO;   // odd lb
        f4 s0 = f4{0.f,0.f,0.f,0.f}, s1 = f4{0.f,0.f,0.f,0.f};
#pragma unroll
        for (int lb2 = 0; lb2 < 8; ++lb2) {
          short8 a0 = frag_ld(pe + lb2 * 64);
          short8 a1 = frag_ld(pe + lb2 * 64 + 16 * 512);
          s0 = __builtin_amdgcn_mfma_f32_16x16x32_bf16(a0, qf[2*lb2], s0, 0, 0, 0);
          s1 = __builtin_amdgcn_mfma_f32_16x16x32_bf16(a1, qf[2*lb2], s1, 0, 0, 0);
          short8 a2 = frag_ld(po + lb2 * 64);
          short8 a3 = frag_ld(po + lb2 * 64 + 16 * 512);
          s0 = __builtin_amdgcn_mfma_f32_16x16x32_bf16(a2, qf[2*lb2+1], s0, 0, 0, 0);
          s1 = __builtin_amdgcn_mfma_f32_16x16x32_bf16(a3, qf[2*lb2+1], s1, 0, 0, 0);
        }

        // ---- causal mask: key = t*32 + chain*16 + quad*4 + r, q = q0+lp ----
        if (t == tmax) {
          const int k0 = t * 32, q = q0 + lp;
#pragma unroll
          for (int r = 0; r < 4; ++r) {
            if (k0 + quad * 4 + r > q)      s0[r] = -3e38f;
            if (k0 + 16 + quad * 4 + r > q) s1[r] = -3e38f;
          }
        }

        // ---- online softmax, defer-max (rescale deferred to pair phase) ----
        float tm = fmaxf(fmaxf(fmaxf(s0[0], s0[1]), fmaxf(s0[2], s0[3])),
                         fmaxf(fmaxf(s1[0], s1[1]), fmaxf(s1[2], s1[3])));
        tm = fmaxf(tm, __shfl_xor(tm, 16, 64));
        tm = fmaxf(tm, __shfl_xor(tm, 32, 64));
        float al = 1.0f;
        if (__ballot(tm > m_r + 12.0f)) {
          float mn = fmaxf(m_r, tm);
          al = exp2f(m_r - mn);
          l_r *= al;
          m_r = mn;
        }
        float p0[4], p1[4], rs = 0.f;
#pragma unroll
        for (int r = 0; r < 4; ++r) {
          p0[r] = exp2f(s0[r] - m_r);
          p1[r] = exp2f(s1[r] - m_r);
          rs += p0[r] + p1[r];
        }
        rs += __shfl_xor(rs, 16, 64);
        rs += __shfl_xor(rs, 32, 64);
        l_r += rs;

        // ---- P^T -> pair LDS [q32 = ph*16+lp][key]; alpha -> Axf ----
        *(uint2*)&Pp[p][ph*16 + lp][quad * 4] =
            make_uint2(f2bf2(p0[0], p0[1]), f2bf2(p0[2], p0[3]));
        *(uint2*)&Pp[p][ph*16 + lp][16 + quad * 4] =
            make_uint2(f2bf2(p1[0], p1[1]), f2bf2(p1[2], p1[3]));
        if (lane < 16) Axf[p][ph*16 + lane] = al;
      }
      __syncthreads();   // barrier A: P/alpha pair-visible; DMA t+1 drained

      if (t <= tmax) {
        // ---- pair-wide rescale: alpha for q32 = la (may be other wave's) --
        float alx = Axf[p][la];
        if (__ballot(alx < 1.0f)) {
#pragma unroll
          for (int ct = 0; ct < 8; ++ct)
#pragma unroll
            for (int j = 0; j < 16; ++j) O32[ct][j] *= alx;
        }

        // ---- PV 32x32x16: O^T[lat half][q32] += V^T * P ----
        short8 pb0 = frag_ld(&Pp[p][la][hi * 8]);
        short8 pb1 = frag_ld(&Pp[p][la][16 + hi * 8]);
        const bf16* KtB = KsT[bf] + pvBase;
#pragma unroll
        for (int lb = 0; lb < 8; ++lb) {
          short8 a0 = frag_ld(KtB + lb * 1024 + offk0);
          O32[lb] = __builtin_amdgcn_mfma_f32_32x32x16_bf16(a0, pb0, O32[lb], 0, 0, 0);
          short8 a1 = frag_ld(KtB + lb * 1024 + offk1);
          O32[lb] = __builtin_amdgcn_mfma_f32_32x32x16_bf16(a1, pb1, O32[lb], 0, 0, 0);
        }
      }
      __syncthreads();   // barrier B: round close, buffers reusable
    }

    // ---- epilogue: exchange l across pair; transpose O via Ks[1] slice ----
    if (lane < 16) Axf[p][ph*16 + lane] = l_r;
    __syncthreads();                         // l visible; Ks[1]/KsT[1] dead
    {
      float linv = 1.0f / Axf[p][la];
      u32* Ex = (u32*)&Ks[1][0] + w * 640;   // per-wave [32 q][20 u32] slice
      const int qrow = lane >> 1, seg = lane & 1;
#pragma unroll
      for (int lb = 0; lb < 8; ++lb) {
        // write: lane holds 16 values for q = la; rows (reg&3)+8*(reg>>2)+4hi
#pragma unroll
        for (int rq = 0; rq < 4; ++rq) {
          float o0 = O32[lb][4*rq + 0] * linv, o1 = O32[lb][4*rq + 1] * linv;
          float o2 = O32[lb][4*rq + 2] * linv, o3 = O32[lb][4*rq + 3] * linv;
          *(uint2*)&Ex[la * 20 + rq * 4 + hi * 2] =
              make_uint2(f2bf2(o0, o1), f2bf2(o2, o3));
        }
        asm volatile("s_waitcnt lgkmcnt(0)" ::: "memory");
        uint4 v0 = *(const uint4*)&Ex[qrow * 20 + seg * 8];
        uint4 v1 = *(const uint4*)&Ex[qrow * 20 + seg * 8 + 4];
        bf16* dst = qbaseP + (long)qrow * kL + L0 + lb * 32 + seg * 16;
        *(uint4*)dst = v0;
        *(uint4*)(dst + 8) = v1;
        asm volatile("s_waitcnt lgkmcnt(0)" ::: "memory");
      }
    }
    __syncthreads();     // half boundary: epilogue done before next prologue
  }
}

// ---------------------------------------------------------------------------
extern "C" void kernel_launch(void* const* d_in, const int* in_sizes, int n_in,
                              void* d_out, int out_size, void* d_ws, size_t ws_size,
                              hipStream_t stream)
{
  const float* x     = (const float*)d_in[0];
  const float* W_dq  = (const float*)d_in[1];
  const float* W_uq  = (const float*)d_in[2];
  const float* W_dkv = (const float*)d_in[3];
  const float* W_uk  = (const float*)d_in[4];
  const float* W_uv  = (const float*)d_in[5];
  const float* W_o   = (const float*)d_in[6];

  float* y_out   = (float*)d_out;
  float* ckv_out = y_out + (long)kB * kT * kC;

  // workspace layout (max 101,711,872 B, proven bound)
  char* ws = (char*)d_ws;
  bf16* q_lat  = (bf16*)(ws + 0);            // 64 MB  (y_lat in place)
  bf16* ckv_b  = (bf16*)(ws + 67108864);     //  4 MB
  bf16* ckvT   = (bf16*)(ws + 71303168);     //  4 MB
  bf16* xb     = (bf16*)(ws + 75497472);     //  8 MB
  bf16* q_lowb = (bf16*)(ws + 83886080);     //  4 MB
  bf16* qfullb = (bf16*)(ws + 88080384);     //  8 MB (scratch overlap below)
  bf16* W_uqTb = (bf16*)(ws + 88080384);     //  1 MB  [dead before qfullb write]
  bf16* W_ukTb = (bf16*)(ws + 89128960);     //  1 MB
  bf16* W_uvTb = (bf16*)(ws + 90177536);     //  1 MB
  bf16* W_dqTb = (bf16*)(ws + 91226112);     //  1 MB
  bf16* W_ob   = (bf16*)(ws + 92274688);     //  2 MB
  bf16* tmpT   = (bf16*)(ws + 94371840);     // 0.5 MB
  bf16* k_effT = (bf16*)(ws + 96468992);     //  1 MB  [512 l][1024 c]
  bf16* v_effT = (bf16*)(ws + 97517568);     //  1 MB  [1024 j][512 l]
  bf16* W_dqb  = (bf16*)(ws + 98566144);     //  1 MB
  bf16* W_uqb  = (bf16*)(ws + 99614720);     //  1 MB
  bf16* W_dkvb = (bf16*)(ws + 100663296);    //  1 MB

  const dim3 blk(256);
  const long TC = (long)kT * kC, TL = (long)kT * kL;
  const float kScale = 0.125f * 1.44269504088896f;   // 1/sqrt(hs) * log2(e)

  casts_all<<<dim3(6656), blk, 0, stream>>>(
      x, W_dq, W_uq, W_dkv, W_o, xb, W_dqb, W_uqb, W_dkvb, W_ob);
  tcasts_all<<<dim3(32, 32, 4), blk, 0, stream>>>(
      W_uq, W_uk, W_uv, W_dq, W_uqTb, W_ukTb, W_uvTb, W_dqTb);

  mm_nt<bf16><<<dim3(8, 8, 1), blk, 0, stream>>>(
      W_ukTb, 1024, 0, 0, W_uqTb, 1024, 0, 0, tmpT, 512, 0, 0, 1024, 1.0f);
  mm_nt<bf16><<<dim3(8, 16, 1), blk, 0, stream>>>(
      tmpT, 512, 0, 0, W_dqTb, 512, 0, 0, k_effT, 1024, 0, 0, 512, kScale);
  mm_nt<bf16><<<dim3(16, 8, 1), blk, 0, stream>>>(
      W_ob, 1024, 0, 0, W_uvTb, 1024, 0, 0, v_effT, 512, 0, 0, 1024, 1.0f);
  mm_nt<bf16><<<dim3(64, 8, 1), blk, 0, stream>>>(
      xb, 1024, 0, 0, W_dqb, 1024, 0, 0, q_lowb, 512, 0, 0, 1024, 1.0f);
  mm_nt<bf16><<<dim3(64, 16, 1), blk, 0, stream>>>(
      q_lowb, 512, 0, 0, W_uqb, 512, 0, 0, qfullb, 1024, 0, 0, 512, 1.0f);
  // c_kv -> bf16 ckv_b directly (no early d_out write)
  mm_nt<bf16><<<dim3(64, 8, 1), blk, 0, stream>>>(
      xb, 1024, 0, 0, W_dkvb, 1024, 0, 0, ckv_b, 512, 0, 0, 1024, 1.0f);
  transpose_ckv<<<dim3(64, 16, 2), blk, 0, stream>>>(ckv_b, ckvT);
  mm_nt<bf16><<<dim3(32, 8, 32), blk, 0, stream>>>(
      qfullb, 1024, TC, 64,
      k_effT, 1024, 0, 64,
      q_lat, 512, (long)kNH * TL, TL,
      64, 1.0f);
  flash_mfma<<<dim3(8, 16, 2), dim3(512), 0, stream>>>(q_lat, ckv_b, ckvT);
  mm_nt<float><<<dim3(32, 1, 32), blk, 0, stream>>>(
      q_lat, 512, (long)kNH * TL, TL,
      v_effT, 512, 0, (long)64 * 512,
      y_out, 1024, TC, 64,
      512, 1.0f);
  // FINAL kernel: write the fp32 c_kv output tail last.
  upcast_kernel<<<dim3(2048), blk, 0, stream>>>(ckv_b, ckv_out, 2097152);

  (void)in_sizes; (void)n_in; (void)out_size; (void)ws_size;
}

// Round 5
// 429.067 us; speedup vs baseline: 1.0508x; 1.0138x over previous
//
#include <hip/hip_runtime.h>
#include <hip/hip_bf16.h>

// MLA absorbed causal attention, MI355X round 10:
//  flash v8: v7 + counted-vmcnt raw barriers (T3/T4). __syncthreads drained
//  vmcnt(0) at BOTH per-round barriers, force-landing the t+1 prefetch DMAs
//  mid-round (exposed latency 2x/round). Now: issue Ks(t+1) then KsT(t+1);
//  barrier A = s_waitcnt vmcnt(8) lgkmcnt(0) + raw s_barrier (drains only
//  KsT(t), P visible); barrier B = vmcnt(4) (drains only Ks(t+1); KsT(t+1)
//  stays in flight until next round's A). Last round / prologue use vmcnt(0)/
//  vmcnt(4). Compute paths identical to v7 (passed, 262 us).
// fp32 I/O. d_out = [ y (2*2048*1024) | c_kv (2*2048*512) ] fp32.

using bf16 = __hip_bfloat16;
using u32  = unsigned int;
using short8 = __attribute__((ext_vector_type(8))) short;   // 8 bf16 (4 VGPRs)
using f4     = __attribute__((ext_vector_type(4))) float;   // 16x16 accumulator
using f16v   = __attribute__((ext_vector_type(16))) float;  // 32x32 accumulator

static constexpr int kB  = 2;
static constexpr int kT  = 2048;
static constexpr int kC  = 1024;
static constexpr int kNH = 16;
static constexpr int kL  = 512;

__device__ inline u32 f2bf2(float a, float b) {
  bf16 ha = __float2bfloat16(a), hb = __float2bfloat16(b);
  unsigned short ua, ub;
  __builtin_memcpy(&ua, &ha, 2);
  __builtin_memcpy(&ub, &hb, 2);
  return (u32)ua | ((u32)ub << 16);
}
__device__ inline unsigned short f2bf(float x) {
  bf16 h = __float2bfloat16(x);
  unsigned short u; __builtin_memcpy(&u, &h, 2);
  return u;
}
__device__ inline short8 frag_ld(const void* p) {   // 16B aligned -> ds/global b128
  short8 r; __builtin_memcpy(&r, p, 16); return r;
}
// async global->LDS DMA, 16 B/lane. dest = wave-uniform base + lane*16.
__device__ inline void g2lds16(const bf16* g, bf16* l) {
  __builtin_amdgcn_global_load_lds(
      (const __attribute__((address_space(1))) u32*)g,
      (__attribute__((address_space(3))) u32*)l, 16, 0, 0);
}

// ---- fused flat casts: x, W_dq, W_uq, W_dkv, W_o -> bf16 ----
__global__ __launch_bounds__(256)
void casts_all(const float* __restrict__ x,   const float* __restrict__ wdq,
               const float* __restrict__ wuq, const float* __restrict__ wdkv,
               const float* __restrict__ wo,
               bf16* __restrict__ xb,   bf16* __restrict__ wdqb,
               bf16* __restrict__ wuqb, bf16* __restrict__ wdkvb,
               bf16* __restrict__ wob)
{
  long i = (long)(blockIdx.x * 256 + threadIdx.x) * 4;
  const float* s; bf16* d; long off;
  if      (i < 4194304) { s = x;    d = xb;    off = i; }
  else if (i < 4718592) { s = wdq;  d = wdqb;  off = i - 4194304; }
  else if (i < 5242880) { s = wuq;  d = wuqb;  off = i - 4718592; }
  else if (i < 5767168) { s = wdkv; d = wdkvb; off = i - 5242880; }
  else                  { s = wo;   d = wob;   off = i - 5767168; }
  float4 v = *(const float4*)(s + off);
  *(uint2*)((u32*)d + off / 2) = make_uint2(f2bf2(v.x, v.y), f2bf2(v.z, v.w));
}

// bf16 -> fp32 upcast (final c_kv output write). n multiple of 1024.
__global__ __launch_bounds__(256)
void upcast_kernel(const bf16* __restrict__ src, float* __restrict__ dst, int n)
{
  int i = (blockIdx.x * 256 + threadIdx.x) * 4;
  if (i < n) {
    uint2 v = *(const uint2*)((const u32*)src + i / 2);
    float4 o;
    o.x = __uint_as_float(v.x << 16);
    o.y = __uint_as_float(v.x & 0xffff0000u);
    o.z = __uint_as_float(v.y << 16);
    o.w = __uint_as_float(v.y & 0xffff0000u);
    *(float4*)(dst + i) = o;
  }
}

// ---- fused transpose-casts: z selects (src,dst,R,C); guards for shape ----
__global__ __launch_bounds__(256)
void tcasts_all(const float* __restrict__ wuq, const float* __restrict__ wuk,
                const float* __restrict__ wuv, const float* __restrict__ wdq,
                bf16* __restrict__ uqT, bf16* __restrict__ ukT,
                bf16* __restrict__ uvT, bf16* __restrict__ dqT)
{
  const int z = blockIdx.z;
  const float* src = z == 0 ? wuq : z == 1 ? wuk : z == 2 ? wuv : wdq;
  bf16* dst        = z == 0 ? uqT : z == 1 ? ukT : z == 2 ? uvT : dqT;
  const int R = (z == 3) ? 512 : 1024, C = (z == 3) ? 1024 : 512;
  const int r0 = blockIdx.x * 32, c0 = blockIdx.y * 32;
  if (r0 >= R || c0 >= C) return;
  __shared__ float s[32][33];
  const int x = threadIdx.x & 31, y = threadIdx.x >> 5;   // y: 0..7
#pragma unroll
  for (int i = 0; i < 4; ++i)
    s[y*4 + i][x] = src[(long)(r0 + y*4 + i) * C + c0 + x];
  __syncthreads();
  unsigned short* dp = (unsigned short*)dst;
#pragma unroll
  for (int i = 0; i < 4; ++i)
    dp[(long)(c0 + y*4 + i) * R + r0 + x] = f2bf(s[x][y*4 + i]);
}

// ckv [b][2048][512] -> ckvT [b][512][2048] (bf16).
__global__ __launch_bounds__(256)
void transpose_ckv(const bf16* __restrict__ src, bf16* __restrict__ dst)
{
  __shared__ unsigned short s[32][33];
  const int b = blockIdx.z, t0 = blockIdx.x * 32, l0 = blockIdx.y * 32;
  const int x = threadIdx.x & 31, y = threadIdx.x >> 5;
  const unsigned short* sp = (const unsigned short*)(src + (long)b * kT * kL);
  unsigned short* dp = (unsigned short*)(dst + (long)b * kL * kT);
#pragma unroll
  for (int i = 0; i < 4; ++i)
    s[y*4 + i][x] = sp[(long)(t0 + y*4 + i) * kL + l0 + x];
  __syncthreads();
#pragma unroll
  for (int i = 0; i < 4; ++i)
    dp[(long)(l0 + y*4 + i) * kT + t0 + x] = s[x][y*4 + i];
}

// ---------------------------------------------------------------------------
// NT MFMA GEMM (round-3 proven): C[m][n] = alpha * sum_k A[m][k] * B[n][k].
// ---------------------------------------------------------------------------
template<typename TCe>
__global__ __launch_bounds__(256)
void mm_nt(const bf16* __restrict__ A, int lda, long aHi, long aLo,
           const bf16* __restrict__ Bm, int ldb, long bHi, long bLo,
           TCe* __restrict__ Cm, int ldc, long cHi, long cLo,
           int K, float alpha)
{
  const int z = blockIdx.z;
  A  += (long)(z >> 4) * aHi + (long)(z & 15) * aLo;
  Bm += (long)(z >> 4) * bHi + (long)(z & 15) * bLo;
  Cm += (long)(z >> 4) * cHi + (long)(z & 15) * cLo;

  __shared__ __align__(16) bf16 As[64][72];
  __shared__ __align__(16) bf16 Bs[64][72];

  const int tid = threadIdx.x;
  const int w = tid >> 6, lane = tid & 63;
  const int quad = lane >> 4, lp = lane & 15;
  const int m0 = blockIdx.x * 64, n0 = blockIdx.y * 64;
  const int row = tid >> 2, cseg = (tid & 3) * 16;

  f4 acc[4];
#pragma unroll
  for (int i = 0; i < 4; ++i) acc[i] = f4{0.f, 0.f, 0.f, 0.f};

  for (int k0 = 0; k0 < K; k0 += 64) {
    const bf16* ag = A  + (long)(m0 + row) * lda + k0 + cseg;
    const bf16* bg = Bm + (long)(n0 + row) * ldb + k0 + cseg;
    uint4 a0 = *(const uint4*)ag, a1 = *(const uint4*)(ag + 8);
    uint4 b0 = *(const uint4*)bg, b1 = *(const uint4*)(bg + 8);
    __syncthreads();
    *(uint4*)&As[row][cseg] = a0; *(uint4*)&As[row][cseg + 8] = a1;
    *(uint4*)&Bs[row][cseg] = b0; *(uint4*)&Bs[row][cseg + 8] = b1;
    __syncthreads();

    short8 af0 = frag_ld(&As[w*16 + lp][quad * 8]);
    short8 af1 = frag_ld(&As[w*16 + lp][32 + quad * 8]);
#pragma unroll
    for (int nb = 0; nb < 4; ++nb) {
      short8 bf0 = frag_ld(&Bs[nb*16 + lp][quad * 8]);
      short8 bf1 = frag_ld(&Bs[nb*16 + lp][32 + quad * 8]);
      acc[nb] = __builtin_amdgcn_mfma_f32_16x16x32_bf16(af0, bf0, acc[nb], 0, 0, 0);
      acc[nb] = __builtin_amdgcn_mfma_f32_16x16x32_bf16(af1, bf1, acc[nb], 0, 0, 0);
    }
  }
#pragma unroll
  for (int nb = 0; nb < 4; ++nb)
#pragma unroll
    for (int r = 0; r < 4; ++r) {
      float v = alpha * acc[nb][r];
      long off = (long)(m0 + w*16 + quad*4 + r) * ldc + n0 + nb*16 + lp;
      if constexpr (__is_same(TCe, float)) Cm[off] = v;
      else ((unsigned short*)Cm)[off] = f2bf(v);
    }
}

// ---------------------------------------------------------------------------
// MFMA flash attention v8: 512-thread WG (8 waves = 4 pairs), double-buffered
// DMA staging with COUNTED vmcnt raw barriers.
// Pair p = waves {2p, 2p+1} owns 32 queries; ph = w&1 owns lat half for PV.
// Round: issue Ks(t+1) then KsT(t+1) -> QK(16x16) + softmax + P/alpha to pair
// LDS -> [vmcnt(8) lgkm(0); s_barrier]  (drains KsT(t) only)
//      -> rescale + PV(32x32x16)        (KsT(t+1) still in flight)
//      -> [vmcnt(4) lgkm(0); s_barrier] (drains Ks(t+1) only).
// Ks[32][512]: phys 16B-block v of row r holds global block v ^ (r&7).
// KsT[512][32]: phys seg s of row rr holds global seg s ^ ((rr>>1)&3).
// Epilogue: per-wave transpose slice aliased on Ks[1] (dead at epilogue).
// ---------------------------------------------------------------------------
__global__ __launch_bounds__(512, 2)
void flash_mfma(bf16* __restrict__ qlat, const bf16* __restrict__ ckv,
                const bf16* __restrict__ ckvT)
{
  const int jj = blockIdx.x, h = blockIdx.y, b = blockIdx.z;
  const int tid = threadIdx.x;
  const int w = tid >> 6, lane = tid & 63;
  const int quad = lane >> 4, lp = lane & 15;
  const int hi = lane >> 5, la = lane & 31;
  const int p = w >> 1, ph = w & 1;         // pair index, lat-half index
  const int L0 = ph * 256;                  // PV lat-half base

  __shared__ __align__(16) bf16 Ks[2][32 * 512];           // 64 KB
  __shared__ __align__(16) bf16 KsT[2][512 * 32];          // 64 KB
  __shared__ __align__(16) unsigned short Pp[4][32][40];   // 10 KB pair P
  __shared__ float Axf[4][32];                             // pair alpha / l

  const bf16* ckb = ckv  + (long)b * kT * kL;
  const bf16* ckt = ckvT + (long)b * kL * kT;

  // per-lane staging constants (element units)
  int ksOff[4], ktRow[4];
#pragma unroll
  for (int i = 0; i < 4; ++i) {
    int r = w * 4 + i;                              // Ks row 0..31
    ksOff[i] = r * 512 + ((lane & ~7) | ((lane ^ r) & 7)) * 8;
    ktRow[i] = (w * 4 + i) * 16 + (lane >> 2);      // KsT row 0..511
  }
  const int ktSeg = ((lane & 3) ^ ((lane >> 3) & 3)) * 8;   // lane-only

  // QK A-frag swizzle decomposition (v6, proven)
  const int cA    = lp & 7;
  const int laneA = lp * 512 + (quad ^ (cA & 3)) * 8;
  const int pOffE = (cA >> 2) * 32;
  const int pOffO = 32 - pOffE;

  // PV A-frag lane constants: read KsT[L0 + lb*32 + la][seg], seg swizzled
  const int cs = (la >> 1) & 3;
  const int pvBase = (L0 + la) * 32;                // + lb*1024 + offk
  const int offk0 = ((0 + hi) ^ cs) * 8;            // kstep 0 (keys 0-15)
  const int offk1 = ((2 + hi) ^ cs) * 8;            // kstep 1 (keys 16-31)

  for (int half = 0; half < 2; ++half) {
    const int stripe = half ? (15 - jj) : jj;
    const int qb = 8 * stripe + w, q0 = qb * 16;           // wave's 16 queries
    const int q0p = stripe * 128 + p * 32;                 // pair's 32 queries
    bf16* qbase  = qlat + (((long)(b * kNH + h)) * kT + q0) * kL;
    bf16* qbaseP = qlat + (((long)(b * kNH + h)) * kT + q0p) * kL;

    // persistent Q fragments (B-operand form): Q[q=lp][lb*32 + quad*8 + j]
    short8 qf[16];
#pragma unroll
    for (int lb = 0; lb < 16; ++lb)
      qf[lb] = frag_ld(qbase + (long)lp * kL + lb * 32 + quad * 8);

    f16v O32[8];
#pragma unroll
    for (int ct = 0; ct < 8; ++ct)
#pragma unroll
      for (int j = 0; j < 16; ++j) O32[ct][j] = 0.f;
    float m_r = -3e38f, l_r = 0.f;

    const int tmax = qb >> 1;                // pair-uniform
    const int nt = 4 * stripe + 4;

    // prologue: stage tile 0 into buffer 0 (Ks first, then KsT)
    {
      const bf16* kbase = ckb;                 // t = 0
#pragma unroll
      for (int i = 0; i < 4; ++i)
        g2lds16(kbase + ksOff[i], &Ks[0][(w * 4 + i) * 512]);
      const bf16* tbase = ckt + ktSeg;
#pragma unroll
      for (int i = 0; i < 4; ++i)
        g2lds16(tbase + (long)ktRow[i] * kT, &KsT[0][(w * 4 + i) * 512]);
    }
    // drain qf + Ks(0); KsT(0) (4 newest) stays in flight until round-0 A
    asm volatile("s_waitcnt vmcnt(4)" ::: "memory");
    __builtin_amdgcn_s_barrier();
    __builtin_amdgcn_sched_barrier(0);

    for (int t = 0; t < nt; ++t) {
      const int bf = t & 1;
      const bool pre = (t + 1 < nt);
      if (pre) {                        // stage t+1: Ks first, then KsT
        const bf16* kbase = ckb + (long)(t + 1) * 32 * kL;
#pragma unroll
        for (int i = 0; i < 4; ++i)
          g2lds16(kbase + ksOff[i], &Ks[bf ^ 1][(w * 4 + i) * 512]);
        const bf16* tbase = ckt + (long)(t + 1) * 32 + ktSeg;
#pragma unroll
        for (int i = 0; i < 4; ++i)
          g2lds16(tbase + (long)ktRow[i] * kT, &KsT[bf ^ 1][(w * 4 + i) * 512]);
      }

      if (t <= tmax) {
        // ---- S^T = K * Q^T : two 16-key m-tiles, hoisted base+imm reads ----
        const bf16* KsB = Ks[bf];
        const bf16* pe = KsB + laneA + pOffE;   // even lb
        const bf16* po = KsB + laneA + pOffO;   // odd lb
        f4 s0 = f4{0.f,0.f,0.f,0.f}, s1 = f4{0.f,0.f,0.f,0.f};
#pragma unroll
        for (int lb2 = 0; lb2 < 8; ++lb2) {
          short8 a0 = frag_ld(pe + lb2 * 64);
          short8 a1 = frag_ld(pe + lb2 * 64 + 16 * 512);
          s0 = __builtin_amdgcn_mfma_f32_16x16x32_bf16(a0, qf[2*lb2], s0, 0, 0, 0);
          s1 = __builtin_amdgcn_mfma_f32_16x16x32_bf16(a1, qf[2*lb2], s1, 0, 0, 0);
          short8 a2 = frag_ld(po + lb2 * 64);
          short8 a3 = frag_ld(po + lb2 * 64 + 16 * 512);
          s0 = __builtin_amdgcn_mfma_f32_16x16x32_bf16(a2, qf[2*lb2+1], s0, 0, 0, 0);
          s1 = __builtin_amdgcn_mfma_f32_16x16x32_bf16(a3, qf[2*lb2+1], s1, 0, 0, 0);
        }

        // ---- causal mask: key = t*32 + chain*16 + quad*4 + r, q = q0+lp ----
        if (t == tmax) {
          const int k0 = t * 32, q = q0 + lp;
#pragma unroll
          for (int r = 0; r < 4; ++r) {
            if (k0 + quad * 4 + r > q)      s0[r] = -3e38f;
            if (k0 + 16 + quad * 4 + r > q) s1[r] = -3e38f;
          }
        }

        // ---- online softmax, defer-max (rescale deferred to pair phase) ----
        float tm = fmaxf(fmaxf(fmaxf(s0[0], s0[1]), fmaxf(s0[2], s0[3])),
                         fmaxf(fmaxf(s1[0], s1[1]), fmaxf(s1[2], s1[3])));
        tm = fmaxf(tm, __shfl_xor(tm, 16, 64));
        tm = fmaxf(tm, __shfl_xor(tm, 32, 64));
        float al = 1.0f;
        if (__ballot(tm > m_r + 12.0f)) {
          float mn = fmaxf(m_r, tm);
          al = exp2f(m_r - mn);
          l_r *= al;
          m_r = mn;
        }
        float p0[4], p1[4], rs = 0.f;
#pragma unroll
        for (int r = 0; r < 4; ++r) {
          p0[r] = exp2f(s0[r] - m_r);
          p1[r] = exp2f(s1[r] - m_r);
          rs += p0[r] + p1[r];
        }
        rs += __shfl_xor(rs, 16, 64);
        rs += __shfl_xor(rs, 32, 64);
        l_r += rs;

        // ---- P^T -> pair LDS [q32 = ph*16+lp][key]; alpha -> Axf ----
        *(uint2*)&Pp[p][ph*16 + lp][quad * 4] =
            make_uint2(f2bf2(p0[0], p0[1]), f2bf2(p0[2], p0[3]));
        *(uint2*)&Pp[p][ph*16 + lp][16 + quad * 4] =
            make_uint2(f2bf2(p1[0], p1[1]), f2bf2(p1[2], p1[3]));
        if (lane < 16) Axf[p][ph*16 + lane] = al;
      }

      // ---- barrier A: P/alpha pair-visible; KsT(t) landed (4 oldest); the
      //      8 newest DMAs (Ks/KsT t+1) stay in flight across the barrier ----
      if (pre) asm volatile("s_waitcnt vmcnt(8) lgkmcnt(0)" ::: "memory");
      else     asm volatile("s_waitcnt vmcnt(0) lgkmcnt(0)" ::: "memory");
      __builtin_amdgcn_s_barrier();
      __builtin_amdgcn_sched_barrier(0);

      if (t <= tmax) {
        // ---- pair-wide rescale: alpha for q32 = la (may be other wave's) --
        float alx = Axf[p][la];
        if (__ballot(alx < 1.0f)) {
#pragma unroll
          for (int ct = 0; ct < 8; ++ct)
#pragma unroll
            for (int j = 0; j < 16; ++j) O32[ct][j] *= alx;
        }

        // ---- PV 32x32x16: O^T[lat half][q32] += V^T * P ----
        short8 pb0 = frag_ld(&Pp[p][la][hi * 8]);
        short8 pb1 = frag_ld(&Pp[p][la][16 + hi * 8]);
        const bf16* KtB = KsT[bf] + pvBase;
#pragma unroll
        for (int lb = 0; lb < 8; ++lb) {
          short8 a0 = frag_ld(KtB + lb * 1024 + offk0);
          O32[lb] = __builtin_amdgcn_mfma_f32_32x32x16_bf16(a0, pb0, O32[lb], 0, 0, 0);
          short8 a1 = frag_ld(KtB + lb * 1024 + offk1);
          O32[lb] = __builtin_amdgcn_mfma_f32_32x32x16_bf16(a1, pb1, O32[lb], 0, 0, 0);
        }
      }

      // ---- barrier B: round close. Ks(t+1) landed (next 4 oldest); KsT(t+1)
      //      keeps flying into next round's barrier A ----
      if (pre) asm volatile("s_waitcnt vmcnt(4) lgkmcnt(0)" ::: "memory");
      else     asm volatile("s_waitcnt vmcnt(0) lgkmcnt(0)" ::: "memory");
      __builtin_amdgcn_s_barrier();
      __builtin_amdgcn_sched_barrier(0);
    }

    // ---- epilogue: exchange l across pair; transpose O via Ks[1] slice ----
    if (lane < 16) Axf[p][ph*16 + lane] = l_r;
    __syncthreads();                         // l visible; Ks[1]/KsT[1] dead
    {
      float linv = 1.0f / Axf[p][la];
      u32* Ex = (u32*)&Ks[1][0] + w * 640;   // per-wave [32 q][20 u32] slice
      const int qrow = lane >> 1, seg = lane & 1;
#pragma unroll
      for (int lb = 0; lb < 8; ++lb) {
        // write: lane holds 16 values for q = la; rows (reg&3)+8*(reg>>2)+4hi
#pragma unroll
        for (int rq = 0; rq < 4; ++rq) {
          float o0 = O32[lb][4*rq + 0] * linv, o1 = O32[lb][4*rq + 1] * linv;
          float o2 = O32[lb][4*rq + 2] * linv, o3 = O32[lb][4*rq + 3] * linv;
          *(uint2*)&Ex[la * 20 + rq * 4 + hi * 2] =
              make_uint2(f2bf2(o0, o1), f2bf2(o2, o3));
        }
        asm volatile("s_waitcnt lgkmcnt(0)" ::: "memory");
        uint4 v0 = *(const uint4*)&Ex[qrow * 20 + seg * 8];
        uint4 v1 = *(const uint4*)&Ex[qrow * 20 + seg * 8 + 4];
        bf16* dst = qbaseP + (long)qrow * kL + L0 + lb * 32 + seg * 16;
        *(uint4*)dst = v0;
        *(uint4*)(dst + 8) = v1;
        asm volatile("s_waitcnt lgkmcnt(0)" ::: "memory");
      }
    }
    __syncthreads();     // half boundary: epilogue done before next prologue
  }
}

// ---------------------------------------------------------------------------
extern "C" void kernel_launch(void* const* d_in, const int* in_sizes, int n_in,
                              void* d_out, int out_size, void* d_ws, size_t ws_size,
                              hipStream_t stream)
{
  const float* x     = (const float*)d_in[0];
  const float* W_dq  = (const float*)d_in[1];
  const float* W_uq  = (const float*)d_in[2];
  const float* W_dkv = (const float*)d_in[3];
  const float* W_uk  = (const float*)d_in[4];
  const float* W_uv  = (const float*)d_in[5];
  const float* W_o   = (const float*)d_in[6];

  float* y_out   = (float*)d_out;
  float* ckv_out = y_out + (long)kB * kT * kC;

  // workspace layout (max 101,711,872 B, proven bound)
  char* ws = (char*)d_ws;
  bf16* q_lat  = (bf16*)(ws + 0);            // 64 MB  (y_lat in place)
  bf16* ckv_b  = (bf16*)(ws + 67108864);     //  4 MB
  bf16* ckvT   = (bf16*)(ws + 71303168);     //  4 MB
  bf16* xb     = (bf16*)(ws + 75497472);     //  8 MB
  bf16* q_lowb = (bf16*)(ws + 83886080);     //  4 MB
  bf16* qfullb = (bf16*)(ws + 88080384);     //  8 MB (scratch overlap below)
  bf16* W_uqTb = (bf16*)(ws + 88080384);     //  1 MB  [dead before qfullb write]
  bf16* W_ukTb = (bf16*)(ws + 89128960);     //  1 MB
  bf16* W_uvTb = (bf16*)(ws + 90177536);     //  1 MB
  bf16* W_dqTb = (bf16*)(ws + 91226112);     //  1 MB
  bf16* W_ob   = (bf16*)(ws + 92274688);     //  2 MB
  bf16* tmpT   = (bf16*)(ws + 94371840);     // 0.5 MB
  bf16* k_effT = (bf16*)(ws + 96468992);     //  1 MB  [512 l][1024 c]
  bf16* v_effT = (bf16*)(ws + 97517568);     //  1 MB  [1024 j][512 l]
  bf16* W_dqb  = (bf16*)(ws + 98566144);     //  1 MB
  bf16* W_uqb  = (bf16*)(ws + 99614720);     //  1 MB
  bf16* W_dkvb = (bf16*)(ws + 100663296);    //  1 MB

  const dim3 blk(256);
  const long TC = (long)kT * kC, TL = (long)kT * kL;
  const float kScale = 0.125f * 1.44269504088896f;   // 1/sqrt(hs) * log2(e)

  casts_all<<<dim3(6656), blk, 0, stream>>>(
      x, W_dq, W_uq, W_dkv, W_o, xb, W_dqb, W_uqb, W_dkvb, W_ob);
  tcasts_all<<<dim3(32, 32, 4), blk, 0, stream>>>(
      W_uq, W_uk, W_uv, W_dq, W_uqTb, W_ukTb, W_uvTb, W_dqTb);

  mm_nt<bf16><<<dim3(8, 8, 1), blk, 0, stream>>>(
      W_ukTb, 1024, 0, 0, W_uqTb, 1024, 0, 0, tmpT, 512, 0, 0, 1024, 1.0f);
  mm_nt<bf16><<<dim3(8, 16, 1), blk, 0, stream>>>(
      tmpT, 512, 0, 0, W_dqTb, 512, 0, 0, k_effT, 1024, 0, 0, 512, kScale);
  mm_nt<bf16><<<dim3(16, 8, 1), blk, 0, stream>>>(
      W_ob, 1024, 0, 0, W_uvTb, 1024, 0, 0, v_effT, 512, 0, 0, 1024, 1.0f);
  mm_nt<bf16><<<dim3(64, 8, 1), blk, 0, stream>>>(
      xb, 1024, 0, 0, W_dqb, 1024, 0, 0, q_lowb, 512, 0, 0, 1024, 1.0f);
  mm_nt<bf16><<<dim3(64, 16, 1), blk, 0, stream>>>(
      q_lowb, 512, 0, 0, W_uqb, 512, 0, 0, qfullb, 1024, 0, 0, 512, 1.0f);
  // c_kv -> bf16 ckv_b directly (no early d_out write)
  mm_nt<bf16><<<dim3(64, 8, 1), blk, 0, stream>>>(
      xb, 1024, 0, 0, W_dkvb, 1024, 0, 0, ckv_b, 512, 0, 0, 1024, 1.0f);
  transpose_ckv<<<dim3(64, 16, 2), blk, 0, stream>>>(ckv_b, ckvT);
  mm_nt<bf16><<<dim3(32, 8, 32), blk, 0, stream>>>(
      qfullb, 1024, TC, 64,
      k_effT, 1024, 0, 64,
      q_lat, 512, (long)kNH * TL, TL,
      64, 1.0f);
  flash_mfma<<<dim3(8, 16, 2), dim3(512), 0, stream>>>(q_lat, ckv_b, ckvT);
  mm_nt<float><<<dim3(32, 1, 32), blk, 0, stream>>>(
      q_lat, 512, (long)kNH * TL, TL,
      v_effT, 512, 0, (long)64 * 512,
      y_out, 1024, TC, 64,
      512, 1.0f);
  // FINAL kernel: write the fp32 c_kv output tail last.
  upcast_kernel<<<dim3(2048), blk, 0, stream>>>(ckv_b, ckv_out, 2097152);

  (void)in_sizes; (void)n_in; (void)out_size; (void)ws_size;
}